// Round 10
// baseline (386.678 us; speedup 1.0000x reference)
//
#include <hip/hip_runtime.h>
#include <math.h>

#define BDIM 2
#define SDIM 4096
#define DMODEL 512
#define NHEAD 8
#define DHEAD 64
#define MROWS (BDIM * SDIM)  // 8192

typedef __attribute__((ext_vector_type(8))) short short8;
typedef __attribute__((ext_vector_type(4))) float f32x4;
typedef __attribute__((ext_vector_type(4))) int i32x4;

union S8I4 {
  short8 s;
  i32x4 i;
};

#define MFMA16(a, b, c) __builtin_amdgcn_mfma_f32_16x16x32_bf16((a), (b), (c), 0, 0, 0)
#define EXP2F(x) __builtin_amdgcn_exp2f(x)

#define SCALE2 0.18033688011112042f  // 0.125 * log2(e)
#define MASKMUL -1.442695040e9f      // -1e9 * log2(e)
#define M0C 16.0f                    // fixed softmax shift (2^-M0 cancels in O/l)

// Truncation split: x = h + l with h = top 16 bits (exact subtraction).
__device__ inline void bf16_split(float x, short& h, short& l) {
  unsigned u = __float_as_uint(x);
  h = (short)(u >> 16);
  float hf = __uint_as_float(u & 0xffff0000u);
  l = (short)(__float_as_uint(x - hf) >> 16);
}

// Paired split+pack via v_perm: .x = (h1<<16)|h0, .y = (l1<<16)|l0.
// Bitwise identical to bf16_split on each value; 6 VALU per 2 values.
__device__ inline int2 bf16_split_pack(float x0, float x1) {
  const unsigned u0 = __float_as_uint(x0), u1 = __float_as_uint(x1);
  const float d0 = x0 - __uint_as_float(u0 & 0xffff0000u);
  const float d1 = x1 - __uint_as_float(u1 & 0xffff0000u);
  int2 r;
  r.x = __builtin_amdgcn_perm(u1, u0, 0x07060302);
  r.y = __builtin_amdgcn_perm(__float_as_uint(d1), __float_as_uint(d0),
                              0x07060302);
  return r;
}

// ---------------------------------------------------------------------------
// One-shot weight prep: W[k][n] fp32 -> Wt_h[n][k], Wt_l[n][k] bf16 h/l.
// ---------------------------------------------------------------------------
__global__ __launch_bounds__(256) void wsplit_kernel(
    const float* __restrict__ W0, const float* __restrict__ W1,
    const float* __restrict__ W2, const float* __restrict__ W3,
    short* __restrict__ T0h, short* __restrict__ T0l, short* __restrict__ T1h,
    short* __restrict__ T1l, short* __restrict__ T2h, short* __restrict__ T2l,
    short* __restrict__ T3h, short* __restrict__ T3l) {
  __shared__ short Th[64 * 72], Tl[64 * 72];
  const int tid = threadIdx.x;
  const int k0 = blockIdx.x * 64;
  const int n0 = blockIdx.y * 64;
  const int z = blockIdx.z;
  const float* W = (z == 0) ? W0 : (z == 1) ? W1 : (z == 2) ? W2 : W3;
  short* Oh = (z == 0) ? T0h : (z == 1) ? T1h : (z == 2) ? T2h : T3h;
  short* Ol = (z == 0) ? T0l : (z == 1) ? T1l : (z == 2) ? T2l : T3l;

  {
    const int r = tid >> 2;
    const int c16 = (tid & 3) * 16;
    short8 h0, h1, l0, l1;
#pragma unroll
    for (int g = 0; g < 2; g++) {
      const f32x4 a = *(const f32x4*)(W + (size_t)(k0 + r) * DMODEL + n0 + c16 + g * 8);
      const f32x4 b = *(const f32x4*)(W + (size_t)(k0 + r) * DMODEL + n0 + c16 + g * 8 + 4);
      short8& hh = g ? h1 : h0;
      short8& ll = g ? l1 : l0;
#pragma unroll
      for (int j = 0; j < 4; j++) {
        short x, y;
        bf16_split(a[j], x, y);
        hh[j] = x;
        ll[j] = y;
        bf16_split(b[j], x, y);
        hh[4 + j] = x;
        ll[4 + j] = y;
      }
    }
    *(short8*)&Th[r * 72 + c16] = h0;
    *(short8*)&Th[r * 72 + c16 + 8] = h1;
    *(short8*)&Tl[r * 72 + c16] = l0;
    *(short8*)&Tl[r * 72 + c16 + 8] = l1;
  }
  __syncthreads();
  {
    const int n = tid >> 2;
    const int kc = (tid & 3) * 16;
    short8 h0, h1, l0, l1;
#pragma unroll
    for (int i = 0; i < 8; i++) {
      h0[i] = Th[(kc + i) * 72 + n];
      h1[i] = Th[(kc + 8 + i) * 72 + n];
      l0[i] = Tl[(kc + i) * 72 + n];
      l1[i] = Tl[(kc + 8 + i) * 72 + n];
    }
    short* dh = Oh + (size_t)(n0 + n) * DMODEL + k0 + kc;
    short* dl = Ol + (size_t)(n0 + n) * DMODEL + k0 + kc;
    *(short8*)dh = h0;
    *(short8*)(dh + 8) = h1;
    *(short8*)dl = l0;
    *(short8*)(dl + 8) = l1;
  }
}

// ---------------------------------------------------------------------------
// MFMA bf16x3 GEMM, flash-style staging (R9 version, kept).
// ---------------------------------------------------------------------------
__global__ __launch_bounds__(256, 2) void proj5_kernel(
    const int mode_sel, const float* __restrict__ X0,
    const float* __restrict__ X1, const float* __restrict__ X2,
    const short* __restrict__ Wth0, const short* __restrict__ Wth1,
    const short* __restrict__ Wth2, const short* __restrict__ Wtl0,
    const short* __restrict__ Wtl1, const short* __restrict__ Wtl2,
    const float* __restrict__ bias0, const float* __restrict__ bias1,
    const float* __restrict__ bias2, float* __restrict__ out,
    short* __restrict__ qoh, short* __restrict__ qol, short* __restrict__ koh,
    short* __restrict__ kol, short* __restrict__ vth, short* __restrict__ vtl) {
  __shared__ short L[18432];
  const int tid = threadIdx.x;
  const int lane = tid & 63;
  const int w = tid >> 6;  // 0..3
  const int lane15 = lane & 15;
  const int quad = lane >> 4;
  const int m0 = blockIdx.x * 64;
  const int n0 = blockIdx.y * 128;
  const int z = blockIdx.z;
  const int mode = (mode_sel >= 0) ? mode_sel : (z == 2 ? 2 : 1);
  const float* X = (z == 0) ? X0 : (z == 1) ? X1 : X2;
  const short* Wth = (z == 0) ? Wth0 : (z == 1) ? Wth1 : Wth2;
  const short* Wtl = (z == 0) ? Wtl0 : (z == 1) ? Wtl1 : Wtl2;
  const float* bias = (z == 0) ? bias0 : (z == 1) ? bias1 : bias2;
  short* oh = (z == 0) ? qoh : koh;
  short* ol = (z == 0) ? qol : kol;
  const int wm = (w >> 1) * 32;
  const int wn = (w & 1) * 64;

  const int rA0 = tid >> 3, csA = tid & 7;
  const int rA1 = 32 + rA0;
  const int rB0 = tid >> 2, csB = tid & 3;
  const int rB1 = 64 + rB0;
  const float* gA0 = X + (size_t)(m0 + rA0) * DMODEL + csA * 4;
  const float* gA1 = X + (size_t)(m0 + rA1) * DMODEL + csA * 4;
  const short* gB0 = Wth + (size_t)(n0 + rB0) * DMODEL + csB * 8;
  const short* gB1 = Wth + (size_t)(n0 + rB1) * DMODEL + csB * 8;
  const short* gB2 = Wtl + (size_t)(n0 + rB0) * DMODEL + csB * 8;
  const short* gB3 = Wtl + (size_t)(n0 + rB1) * DMODEL + csB * 8;
  const int oA0 = rA0 * 64 + ((csA ^ (rA0 & 7)) * 8);
  const int oA1 = rA1 * 64 + ((csA ^ (rA1 & 7)) * 8);
  const int oB0 = 4096 + rB0 * 32 + ((csB ^ ((rB0 >> 1) & 3)) * 8);
  const int oB1 = 4096 + rB1 * 32 + ((csB ^ ((rB1 >> 1) & 3)) * 8);
  const int oB2 = 4096 + oB0;
  const int oB3 = 4096 + oB1;

  f32x4 c[2][4];
#pragma unroll
  for (int mt = 0; mt < 2; mt++)
#pragma unroll
    for (int nt = 0; nt < 4; nt++) c[mt][nt] = (f32x4){0.f, 0.f, 0.f, 0.f};

  constexpr int NT = DMODEL / 32;  // 16 K-steps

  short8 rg[6];
  rg[0] = *(const short8*)gA0;
  rg[1] = *(const short8*)gA1;
  rg[2] = *(const short8*)gB0;
  rg[3] = *(const short8*)gB1;
  rg[4] = *(const short8*)gB2;
  rg[5] = *(const short8*)gB3;

  for (int t = 0; t < NT; t++) {
    __builtin_amdgcn_s_barrier();
    __builtin_amdgcn_sched_barrier(0);
    *(short8*)&L[oA0] = rg[0];
    *(short8*)&L[oA1] = rg[1];
    *(short8*)&L[oB0] = rg[2];
    *(short8*)&L[oB1] = rg[3];
    *(short8*)&L[oB2] = rg[4];
    *(short8*)&L[oB3] = rg[5];
    if (t + 1 < NT) {
      rg[0] = *(const short8*)(gA0 + (t + 1) * 32);
      rg[1] = *(const short8*)(gA1 + (t + 1) * 32);
      rg[2] = *(const short8*)(gB0 + (t + 1) * 32);
      rg[3] = *(const short8*)(gB1 + (t + 1) * 32);
      rg[4] = *(const short8*)(gB2 + (t + 1) * 32);
      rg[5] = *(const short8*)(gB3 + (t + 1) * 32);
    }
    asm volatile("s_waitcnt lgkmcnt(0)" ::: "memory");
    __builtin_amdgcn_s_barrier();
    __builtin_amdgcn_sched_barrier(0);

    const float* Af = (const float*)L;
    short8 ah[2], al[2], bh[4], bl[4];
#pragma unroll
    for (int mt = 0; mt < 2; mt++) {
      const int r = wm + mt * 16 + lane15;
      const int c0 = ((quad * 2) ^ (r & 7)) * 4;
      const int c1 = ((quad * 2 + 1) ^ (r & 7)) * 4;
      const f32x4 a0 = *(const f32x4*)&Af[r * 32 + c0];
      const f32x4 a1 = *(const f32x4*)&Af[r * 32 + c1];
      S8I4 hh, ll;
      const int2 p0 = bf16_split_pack(a0[0], a0[1]);
      const int2 p1 = bf16_split_pack(a0[2], a0[3]);
      const int2 p2 = bf16_split_pack(a1[0], a1[1]);
      const int2 p3 = bf16_split_pack(a1[2], a1[3]);
      hh.i[0] = p0.x; ll.i[0] = p0.y;
      hh.i[1] = p1.x; ll.i[1] = p1.y;
      hh.i[2] = p2.x; ll.i[2] = p2.y;
      hh.i[3] = p3.x; ll.i[3] = p3.y;
      ah[mt] = hh.s;
      al[mt] = ll.s;
    }
#pragma unroll
    for (int nt = 0; nt < 4; nt++) {
      const int rr = wn + nt * 16 + lane15;
      const int cb = (quad ^ ((rr >> 1) & 3)) * 8;
      bh[nt] = *(const short8*)&L[4096 + rr * 32 + cb];
      bl[nt] = *(const short8*)&L[8192 + rr * 32 + cb];
    }
    __builtin_amdgcn_s_setprio(1);
#pragma unroll
    for (int mt = 0; mt < 2; mt++)
#pragma unroll
      for (int nt = 0; nt < 4; nt++) {
        c[mt][nt] = MFMA16(ah[mt], bh[nt], c[mt][nt]);
        c[mt][nt] = MFMA16(ah[mt], bl[nt], c[mt][nt]);
        c[mt][nt] = MFMA16(al[mt], bh[nt], c[mt][nt]);
      }
    __builtin_amdgcn_s_setprio(0);
  }

  // ---- epilogue ----
  if (mode == 2) {
    __syncthreads();
    short* Lh = L;           // [128][72]
    short* Ll = L + 9216;    // [128][72]
#pragma unroll
    for (int nt = 0; nt < 4; nt++) {
      const int n = wn + nt * 16 + lane15;
      const float bb = bias[n0 + n];
#pragma unroll
      for (int mt = 0; mt < 2; mt++)
#pragma unroll
        for (int r = 0; r < 4; r++) {
          const int m = wm + mt * 16 + quad * 4 + r;
          short x, y;
          bf16_split(c[mt][nt][r] + bb, x, y);
          Lh[n * 72 + m] = x;
          Ll[n * 72 + m] = y;
        }
    }
    __syncthreads();
    const int row = tid >> 1;
    const int half = tid & 1;
    const int n = n0 + row;
    const int hh = n >> 6, d = n & 63;
    const int bidx = m0 >> 12, s0 = m0 & 4095;
    const size_t tbase = ((size_t)(bidx * NHEAD + hh)) * SDIM * DHEAD +
                         (size_t)d * SDIM + s0 + half * 32;
#pragma unroll
    for (int i = 0; i < 4; i++) {
      *(short8*)(vth + tbase + i * 8) =
          *(const short8*)&Lh[row * 72 + half * 32 + i * 8];
      *(short8*)(vtl + tbase + i * 8) =
          *(const short8*)&Ll[row * 72 + half * 32 + i * 8];
    }
    return;
  }

#pragma unroll
  for (int nt = 0; nt < 4; nt++) {
    const int n = n0 + wn + nt * 16 + lane15;
    const float bb = bias[n];
#pragma unroll
    for (int mt = 0; mt < 2; mt++)
#pragma unroll
      for (int r = 0; r < 4; r++) {
        const int m = m0 + wm + mt * 16 + quad * 4 + r;
        const float val = c[mt][nt][r] + bb;
        if (mode == 1) {
          const int bidx = m >> 12;
          const int s = m & 4095;
          const int hh = n >> 6;
          const int d = n & 63;
          const size_t off =
              ((size_t)(bidx * NHEAD + hh) * SDIM + s) * DHEAD + d;
          short x, y;
          bf16_split(val, x, y);
          oh[off] = x;
          ol[off] = y;
        } else {
          out[(size_t)m * DMODEL + n] = val;
        }
      }
  }
}

// ---------------------------------------------------------------------------
// Flash attention, bf16x3 MFMA, fixed-shift softmax.
// R10: SWAPPED QK^T (S^T = mfma(K,Q); same products, same accumulation
// order -> bit-identical S). Output lane layout: col=lane15=q,
// row=quad*4+r=k -> each lane's 4 values are k-consecutive for one q-row,
// so h/l pairs pack PRE-store and the Ps f32 round-trip dies:
//   was: 32 ds_write_b32 + 16 ds_read_b128 + 192 pack-VALU / wave / tile
//   now: 16 ds_write_b64 (conflict-free, verified vs 36-word stride)
//        + 8 ds_read_b128 (16B-aligned, minimal) + 96 pack-VALU.
// Rowsum MFMAs / PV / lr / epilogue untouched -> output bit-identical.
// Mask folded per (nt,r): 16 L1-hot loads (same arithmetic per (q,k)).
// ---------------------------------------------------------------------------
#define KP 72
#define VP 72
#define PW 36  // Ph/Pl row stride in u32 words (16B-aligned rows)

__global__ __launch_bounds__(256, 2) void flash_attn_kernel(
    const short* __restrict__ qhh, const short* __restrict__ qhl,
    const short* __restrict__ khh, const short* __restrict__ khl,
    const short* __restrict__ vth, const short* __restrict__ vtl,
    const float* __restrict__ mask, float* __restrict__ ctx) {
  __shared__ short Ksh[64 * KP], Ksl[64 * KP];
  __shared__ short Vsh[64 * VP], Vsl[64 * VP];
  __shared__ unsigned Ph[128 * PW], Pl[128 * PW];

  const int tid = threadIdx.x;
  const int lane = tid & 63;
  const int w = tid >> 6;
  const int lane15 = lane & 15;
  const int quad = lane >> 4;

  // Bijective XCD swizzle (nwg=512, 512%8==0).
  const int bid = blockIdx.x + 32 * (blockIdx.y + NHEAD * blockIdx.z);
  const int sw = (bid & 7) * 64 + (bid >> 3);
  const int q0 = (sw & 31) * 128;
  const int h = (sw >> 5) & 7;
  const int b = sw >> 8;

  const size_t base = (size_t)(b * NHEAD + h) * SDIM * DHEAD;
  const short* Qh = qhh + base;
  const short* Ql = qhl + base;
  const short* Kh = khh + base;
  const short* Kl = khl + base;
  const short* Vh = vth + base;  // [D][S]
  const short* Vl = vtl + base;
  const float* mb = mask + (size_t)b * SDIM;

  short8 qfh[2][2], qfl[2][2];
#pragma unroll
  for (int mt = 0; mt < 2; mt++) {
    const size_t row = q0 + w * 32 + mt * 16 + lane15;
#pragma unroll
    for (int ks = 0; ks < 2; ks++) {
      qfh[mt][ks] = *(const short8*)(Qh + row * DHEAD + ks * 32 + quad * 8);
      qfl[mt][ks] = *(const short8*)(Ql + row * DHEAD + ks * 32 + quad * 8);
    }
  }

  f32x4 o[2][4];
#pragma unroll
  for (int mt = 0; mt < 2; mt++)
#pragma unroll
    for (int dt = 0; dt < 4; dt++) o[mt][dt] = (f32x4){0.f, 0.f, 0.f, 0.f};
  float lr[2][4];
#pragma unroll
  for (int mt = 0; mt < 2; mt++)
#pragma unroll
    for (int r = 0; r < 4; r++) lr[mt][r] = 0.f;

  short8 onesb;
#pragma unroll
  for (int j = 0; j < 8; j++) onesb[j] = (short)0x3F80;  // bf16 1.0

  const int sr = tid >> 2;
  const int sc = (tid & 3) * 16;

  // prologue: prefetch tile 0 into registers
  short8 rg[8];
  rg[0] = *(const short8*)(Kh + (size_t)sr * DHEAD + sc);
  rg[1] = *(const short8*)(Kh + (size_t)sr * DHEAD + sc + 8);
  rg[2] = *(const short8*)(Kl + (size_t)sr * DHEAD + sc);
  rg[3] = *(const short8*)(Kl + (size_t)sr * DHEAD + sc + 8);
  rg[4] = *(const short8*)(Vh + (size_t)sr * SDIM + sc);
  rg[5] = *(const short8*)(Vh + (size_t)sr * SDIM + sc + 8);
  rg[6] = *(const short8*)(Vl + (size_t)sr * SDIM + sc);
  rg[7] = *(const short8*)(Vl + (size_t)sr * SDIM + sc + 8);

  for (int kt = 0; kt < SDIM / 64; kt++) {
    const int k0 = kt * 64;
    // barrier A: every wave finished reading the previous tile's LDS
    __builtin_amdgcn_s_barrier();
    __builtin_amdgcn_sched_barrier(0);
    *(short8*)&Ksh[sr * KP + sc] = rg[0];
    *(short8*)&Ksh[sr * KP + sc + 8] = rg[1];
    *(short8*)&Ksl[sr * KP + sc] = rg[2];
    *(short8*)&Ksl[sr * KP + sc + 8] = rg[3];
    *(short8*)&Vsh[sr * VP + sc] = rg[4];
    *(short8*)&Vsh[sr * VP + sc + 8] = rg[5];
    *(short8*)&Vsl[sr * VP + sc] = rg[6];
    *(short8*)&Vsl[sr * VP + sc + 8] = rg[7];
    // T14: issue next tile's global loads now (in flight across barriers).
    if (kt + 1 < SDIM / 64) {
      const int k1 = k0 + 64;
      rg[0] = *(const short8*)(Kh + (size_t)(k1 + sr) * DHEAD + sc);
      rg[1] = *(const short8*)(Kh + (size_t)(k1 + sr) * DHEAD + sc + 8);
      rg[2] = *(const short8*)(Kl + (size_t)(k1 + sr) * DHEAD + sc);
      rg[3] = *(const short8*)(Kl + (size_t)(k1 + sr) * DHEAD + sc + 8);
      rg[4] = *(const short8*)(Vh + (size_t)sr * SDIM + k1 + sc);
      rg[5] = *(const short8*)(Vh + (size_t)sr * SDIM + k1 + sc + 8);
      rg[6] = *(const short8*)(Vl + (size_t)sr * SDIM + k1 + sc);
      rg[7] = *(const short8*)(Vl + (size_t)sr * SDIM + k1 + sc + 8);
    }
    // Mask per (nt, r): k = k0 + nt*16 + quad*4 + r (swapped layout rows).
    float mvv[4][4];
#pragma unroll
    for (int nt = 0; nt < 4; nt++)
#pragma unroll
      for (int r = 0; r < 4; r++)
        mvv[nt][r] = fmaf(mb[k0 + nt * 16 + quad * 4 + r], MASKMUL, -M0C);
    // barrier B: LDS writes visible (lgkm only — vmcnt stays outstanding)
    asm volatile("s_waitcnt lgkmcnt(0)" ::: "memory");
    __builtin_amdgcn_s_barrier();
    __builtin_amdgcn_sched_barrier(0);

    // QK^T swapped: S^T = K·Q^T. K is A-operand (row=lane15=k-row),
    // Q is B-operand (col=lane15=q). Same K-fragment reads as before.
    __builtin_amdgcn_s_setprio(1);
#pragma unroll
    for (int nt = 0; nt < 4; nt++) {
      short8 kbh[2], kbl[2];
#pragma unroll
      for (int ks = 0; ks < 2; ks++) {
        const int koff = (nt * 16 + lane15) * KP + ks * 32 + quad * 8;
        kbh[ks] = *(const short8*)&Ksh[koff];
        kbl[ks] = *(const short8*)&Ksl[koff];
      }
#pragma unroll
      for (int mt = 0; mt < 2; mt++) {
        f32x4 acc = (f32x4){0.f, 0.f, 0.f, 0.f};
#pragma unroll
        for (int ks = 0; ks < 2; ks++) {
          acc = MFMA16(kbh[ks], qfh[mt][ks], acc);
          acc = MFMA16(kbl[ks], qfh[mt][ks], acc);
          acc = MFMA16(kbh[ks], qfl[mt][ks], acc);
        }
        // P row (one q = lane15) at ks nt*16+quad*4+{0..3}: k-consecutive.
        const float p0 = EXP2F(fmaf(acc[0], SCALE2, mvv[nt][0]));
        const float p1 = EXP2F(fmaf(acc[1], SCALE2, mvv[nt][1]));
        const float p2 = EXP2F(fmaf(acc[2], SCALE2, mvv[nt][2]));
        const float p3 = EXP2F(fmaf(acc[3], SCALE2, mvv[nt][3]));
        const int2 w01 = bf16_split_pack(p0, p1);
        const int2 w23 = bf16_split_pack(p2, p3);
        const int prow = w * 32 + mt * 16 + lane15;
        const int wo = prow * PW + nt * 8 + quad * 2;
        *(int2*)&Ph[wo] = make_int2(w01.x, w23.x);
        *(int2*)&Pl[wo] = make_int2(w01.y, w23.y);
      }
    }
    __builtin_amdgcn_s_setprio(0);

    // PV A-fragments: direct b128 reads (wave-private rows; compiler
    // inserts lgkmcnt). Word layout matches the MFMA A-operand exactly.
    short8 pah[2][2], pal[2][2];
#pragma unroll
    for (int mt = 0; mt < 2; mt++) {
      const int prow = w * 32 + mt * 16 + lane15;
#pragma unroll
      for (int kf = 0; kf < 2; kf++) {
        pah[mt][kf] = *(const short8*)&Ph[prow * PW + kf * 16 + quad * 4];
        pal[mt][kf] = *(const short8*)&Pl[prow * PW + kf * 16 + quad * 4];
      }
    }

    __builtin_amdgcn_s_setprio(1);
#pragma unroll
    for (int mt = 0; mt < 2; mt++) {
      f32x4 racc = (f32x4){0.f, 0.f, 0.f, 0.f};
#pragma unroll
      for (int kf = 0; kf < 2; kf++) {
        racc = MFMA16(pah[mt][kf], onesb, racc);
        racc = MFMA16(pal[mt][kf], onesb, racc);
      }
#pragma unroll
      for (int r = 0; r < 4; r++) lr[mt][r] += racc[r];
    }

#pragma unroll
    for (int dt = 0; dt < 4; dt++)
#pragma unroll
      for (int kf = 0; kf < 2; kf++) {
        const int voff = (dt * 16 + lane15) * VP + kf * 32 + quad * 8;
        const short8 vbh = *(const short8*)&Vsh[voff];
        const short8 vbl = *(const short8*)&Vsl[voff];
#pragma unroll
        for (int mt = 0; mt < 2; mt++) {
          o[mt][dt] = MFMA16(pah[mt][kf], vbh, o[mt][dt]);
          o[mt][dt] = MFMA16(pah[mt][kf], vbl, o[mt][dt]);
          o[mt][dt] = MFMA16(pal[mt][kf], vbh, o[mt][dt]);
        }
      }
    __builtin_amdgcn_s_setprio(0);
  }

  float inv[2][4];
#pragma unroll
  for (int mt = 0; mt < 2; mt++)
#pragma unroll
    for (int r = 0; r < 4; r++) inv[mt][r] = 1.f / lr[mt][r];
#pragma unroll
  for (int mt = 0; mt < 2; mt++)
#pragma unroll
    for (int dt = 0; dt < 4; dt++)
#pragma unroll
      for (int r = 0; r < 4; r++) {
        const int q = q0 + w * 32 + mt * 16 + quad * 4 + r;
        const int col = h * DHEAD + dt * 16 + lane15;
        ctx[((size_t)b * SDIM + q) * DMODEL + col] = o[mt][dt][r] * inv[mt][r];
      }
}

// ---------------------------------------------------------------------------
extern "C" void kernel_launch(void* const* d_in, const int* in_sizes, int n_in,
                              void* d_out, int out_size, void* d_ws,
                              size_t ws_size, hipStream_t stream) {
  const float* q = (const float*)d_in[0];
  const float* k = (const float*)d_in[1];
  const float* v = (const float*)d_in[2];
  const float* mask = (const float*)d_in[3];
  const float* Wq = (const float*)d_in[4];
  const float* bq = (const float*)d_in[5];
  const float* Wk = (const float*)d_in[6];
  const float* bk = (const float*)d_in[7];
  const float* Wv = (const float*)d_in[8];
  const float* bv = (const float*)d_in[9];
  const float* Wo = (const float*)d_in[10];
  const float* bo = (const float*)d_in[11];
  float* out = (float*)d_out;

  char* W = (char*)d_ws;
  const size_t SZB = (size_t)MROWS * DMODEL * sizeof(short);  // 8 MB
  short* q_h = (short*)(W + 0 * SZB);
  short* q_l = (short*)(W + 1 * SZB);
  short* k_h = (short*)(W + 2 * SZB);
  short* k_l = (short*)(W + 3 * SZB);
  short* vt_h = (short*)(W + 4 * SZB);
  short* vt_l = (short*)(W + 5 * SZB);
  float* ctx = (float*)(W + 6 * SZB);  // fp32, 16 MB = 2*SZB
  const size_t WSZ = (size_t)DMODEL * DMODEL * sizeof(short);  // 512 KB
  char* WT = W + 8 * SZB;
  short* wtq_h = (short*)(WT + 0 * WSZ);
  short* wtq_l = (short*)(WT + 1 * WSZ);
  short* wtk_h = (short*)(WT + 2 * WSZ);
  short* wtk_l = (short*)(WT + 3 * WSZ);
  short* wtv_h = (short*)(WT + 4 * WSZ);
  short* wtv_l = (short*)(WT + 5 * WSZ);
  short* wto_h = (short*)(WT + 6 * WSZ);
  short* wto_l = (short*)(WT + 7 * WSZ);

  wsplit_kernel<<<dim3(DMODEL / 64, DMODEL / 64, 4), 256, 0, stream>>>(
      Wq, Wk, Wv, Wo, wtq_h, wtq_l, wtk_h, wtk_l, wtv_h, wtv_l, wto_h, wto_l);

  // Merged Q/K/V projections (z selects); V writes transposed only.
  proj5_kernel<<<dim3(MROWS / 64, DMODEL / 128, 3), 256, 0, stream>>>(
      -1, q, k, v, wtq_h, wtk_h, wtv_h, wtq_l, wtk_l, wtv_l, bq, bk, bv,
      nullptr, q_h, q_l, k_h, k_l, vt_h, vt_l);

  flash_attn_kernel<<<dim3(SDIM / 128, NHEAD, BDIM), 256, 0, stream>>>(
      q_h, q_l, k_h, k_l, vt_h, vt_l, mask, ctx);

  // Output projection (mode 0), X = ctx.
  proj5_kernel<<<dim3(MROWS / 64, DMODEL / 128, 1), 256, 0, stream>>>(
      0, ctx, nullptr, nullptr, wto_h, nullptr, nullptr, wto_l, nullptr,
      nullptr, bo, nullptr, nullptr, out, nullptr, nullptr, nullptr, nullptr,
      nullptr, nullptr);
}